// Round 1
// baseline (646.135 us; speedup 1.0000x reference)
//
#include <hip/hip_runtime.h>
#include <stdint.h>

#define EMBED 1024
#define HEADS 16
#define HDIM 64
#define BATCH 4
#define SEQ 2048
#define ROWS (BATCH*SEQ)   // 8192

typedef __attribute__((ext_vector_type(8))) __bf16 bf16x8;
typedef __attribute__((ext_vector_type(4))) float f32x4;

__device__ inline unsigned short f2bf(float f) {
    union { float f; unsigned int u; } v; v.f = f;
    unsigned int u = v.u;
    unsigned int r = (u + 0x7FFFu + ((u >> 16) & 1u)) >> 16;
    return (unsigned short)r;
}

// ---------------- fp32 -> bf16 conversion ----------------
__global__ __launch_bounds__(256) void cvt_f32_bf16(const float* __restrict__ src,
                                                    unsigned short* __restrict__ dst,
                                                    int n) {
    int i = (blockIdx.x * 256 + threadIdx.x) * 4;
    if (i < n) {
        float4 v = *(const float4*)(src + i);
        uint2 p;
        p.x = (unsigned)f2bf(v.x) | ((unsigned)f2bf(v.y) << 16);
        p.y = (unsigned)f2bf(v.z) | ((unsigned)f2bf(v.w) << 16);
        *(uint2*)(dst + i) = p;
    }
}

// ---------------- bf16 GEMM, C = A @ B^T + bias ----------------
// A: [M][K] bf16 row-major, B: [N][K] bf16 row-major (i.e. W as stored),
// C: [M][N] bf16 or fp32. Tile 128x128, BK=32, 256 threads (4 waves, 2x2).
template <bool OUT_BF16>
__global__ __launch_bounds__(256) void gemm_bt(const unsigned short* __restrict__ A,
                                               const unsigned short* __restrict__ B,
                                               const float* __restrict__ bias,
                                               void* __restrict__ C,
                                               int M, int N, int K) {
    __shared__ unsigned short As[128 * 32];
    __shared__ unsigned short Bs[128 * 32];

    const int tid  = threadIdx.x;
    const int lane = tid & 63;
    const int wave = tid >> 6;
    const int wm   = wave & 1;
    const int wn   = wave >> 1;
    const int tileM = blockIdx.y * 128;
    const int tileN = blockIdx.x * 128;

    f32x4 acc[4][4] = {};

    for (int k0 = 0; k0 < K; k0 += 32) {
        __syncthreads();
#pragma unroll
        for (int s = 0; s < 2; ++s) {
            int j = tid + s * 256;          // chunk of 8 bf16
            int r = j >> 2;                 // 4 chunks per 32-col row
            int c = (j & 3) * 8;
            uint4 va = *(const uint4*)(A + (size_t)(tileM + r) * K + k0 + c);
            *(uint4*)(As + j * 8) = va;
            uint4 vb = *(const uint4*)(B + (size_t)(tileN + r) * K + k0 + c);
            *(uint4*)(Bs + j * 8) = vb;
        }
        __syncthreads();

        bf16x8 a[4], b[4];
        const int kk = (lane >> 4) * 8;
#pragma unroll
        for (int i = 0; i < 4; ++i) {
            a[i] = *(const bf16x8*)(As + (wm * 64 + i * 16 + (lane & 15)) * 32 + kk);
            b[i] = *(const bf16x8*)(Bs + (wn * 64 + i * 16 + (lane & 15)) * 32 + kk);
        }
#pragma unroll
        for (int i = 0; i < 4; ++i)
#pragma unroll
            for (int jn = 0; jn < 4; ++jn)
                acc[i][jn] = __builtin_amdgcn_mfma_f32_16x16x32_bf16(a[i], b[jn], acc[i][jn], 0, 0, 0);
    }

    // epilogue: C/D layout col = lane&15, row = (lane>>4)*4 + r
#pragma unroll
    for (int i = 0; i < 4; ++i) {
        int row0 = tileM + wm * 64 + i * 16 + ((lane >> 4) << 2);
#pragma unroll
        for (int jn = 0; jn < 4; ++jn) {
            int col = tileN + wn * 64 + jn * 16 + (lane & 15);
            float bv = bias[col];
#pragma unroll
            for (int r = 0; r < 4; ++r) {
                float v = acc[i][jn][r] + bv;
                if (OUT_BF16)
                    ((unsigned short*)C)[(size_t)(row0 + r) * N + col] = f2bf(v);
                else
                    ((float*)C)[(size_t)(row0 + r) * N + col] = v;
            }
        }
    }
}

// ---------------- flash attention ----------------
// One block per (qt, h, b): 64 query rows. 256 threads = 4 waves; wave w owns
// query rows [16w, 16w+16). Iterate 32 key tiles of 64.
__global__ __launch_bounds__(256) void attn(const unsigned short* __restrict__ Q,
                                            const unsigned short* __restrict__ Kp,
                                            const unsigned short* __restrict__ V,
                                            unsigned short* __restrict__ O) {
    __shared__ unsigned short Qs[64 * 64];
    __shared__ unsigned short Ks[64 * 64];
    __shared__ unsigned short Vt[64 * 64];     // Vt[d][key]
    __shared__ unsigned short Ps[4 * 16 * 64]; // per-wave P tile

    const int tid  = threadIdx.x;
    const int lane = tid & 63;
    const int wave = tid >> 6;
    const int qt = blockIdx.x;
    const int h  = blockIdx.y;
    const int b  = blockIdx.z;

    const size_t rowbase = (size_t)b * SEQ;
    const int colbase = h * HDIM;

    // stage Q tile (64x64): 512 chunks of 8 bf16
#pragma unroll
    for (int s = 0; s < 2; ++s) {
        int j = tid + s * 256;
        int r = j >> 3;
        int c = (j & 7) * 8;
        uint4 v = *(const uint4*)(Q + (rowbase + qt * 64 + r) * EMBED + colbase + c);
        *(uint4*)(Qs + j * 8) = v;
    }

    float mrow[4], lrow[4];
#pragma unroll
    for (int r = 0; r < 4; ++r) { mrow[r] = -1e30f; lrow[r] = 0.f; }
    f32x4 oacc[4] = {};

    const float scale = 0.03125f; // 1/sqrt(1024)

    for (int t = 0; t < 32; ++t) {
        __syncthreads();
        // stage K tile
#pragma unroll
        for (int s = 0; s < 2; ++s) {
            int j = tid + s * 256;
            int r = j >> 3;
            int c = (j & 7) * 8;
            uint4 v = *(const uint4*)(Kp + (rowbase + t * 64 + r) * EMBED + colbase + c);
            *(uint4*)(Ks + j * 8) = v;
        }
        // stage V transposed: thread -> row r = tid>>2, cols d0..d0+15
        {
            int r  = tid >> 2;
            int d0 = (tid & 3) * 16;
            const unsigned short* src = V + (rowbase + t * 64 + r) * EMBED + colbase + d0;
            unsigned short tmp[16];
            *(uint4*)(tmp)     = *(const uint4*)(src);
            *(uint4*)(tmp + 8) = *(const uint4*)(src + 8);
#pragma unroll
            for (int dd = 0; dd < 16; ++dd)
                Vt[(d0 + dd) * 64 + r] = tmp[dd];
        }
        __syncthreads();

        // S = Q·K^T for this wave's 16 rows
        f32x4 s_acc[4] = {};
        const int kq = (lane >> 4) * 8;
#pragma unroll
        for (int ks = 0; ks < 2; ++ks) {
            bf16x8 aq = *(const bf16x8*)(Qs + (wave * 16 + (lane & 15)) * 64 + ks * 32 + kq);
#pragma unroll
            for (int nf = 0; nf < 4; ++nf) {
                bf16x8 bk = *(const bf16x8*)(Ks + (nf * 16 + (lane & 15)) * 64 + ks * 32 + kq);
                s_acc[nf] = __builtin_amdgcn_mfma_f32_16x16x32_bf16(aq, bk, s_acc[nf], 0, 0, 0);
            }
        }

        // online softmax (each lane owns 4 rows: (lane>>4)*4 + r within wave)
        float e[4][4];
        float rmax[4];
#pragma unroll
        for (int r = 0; r < 4; ++r) rmax[r] = -1e30f;
#pragma unroll
        for (int nf = 0; nf < 4; ++nf)
#pragma unroll
            for (int r = 0; r < 4; ++r) {
                float x = s_acc[nf][r] * scale;
                e[nf][r] = x;
                rmax[r] = fmaxf(rmax[r], x);
            }
#pragma unroll
        for (int off = 1; off < 16; off <<= 1)
#pragma unroll
            for (int r = 0; r < 4; ++r)
                rmax[r] = fmaxf(rmax[r], __shfl_xor(rmax[r], off));
        float alpha[4];
#pragma unroll
        for (int r = 0; r < 4; ++r) {
            float mnew = fmaxf(mrow[r], rmax[r]);
            alpha[r] = __expf(mrow[r] - mnew);
            mrow[r] = mnew;
        }
        float rsum[4] = {0.f, 0.f, 0.f, 0.f};
#pragma unroll
        for (int nf = 0; nf < 4; ++nf)
#pragma unroll
            for (int r = 0; r < 4; ++r) {
                float p = __expf(e[nf][r] - mrow[r]);
                e[nf][r] = p;
                rsum[r] += p;
            }
#pragma unroll
        for (int off = 1; off < 16; off <<= 1)
#pragma unroll
            for (int r = 0; r < 4; ++r)
                rsum[r] += __shfl_xor(rsum[r], off);
#pragma unroll
        for (int r = 0; r < 4; ++r)
            lrow[r] = lrow[r] * alpha[r] + rsum[r];
#pragma unroll
        for (int df = 0; df < 4; ++df)
#pragma unroll
            for (int r = 0; r < 4; ++r)
                oacc[df][r] *= alpha[r];

        // write P (C-layout) to LDS as bf16 in A-operand-readable layout
        unsigned short* pw = Ps + wave * 16 * 64;
#pragma unroll
        for (int nf = 0; nf < 4; ++nf) {
            int key = nf * 16 + (lane & 15);
#pragma unroll
            for (int r = 0; r < 4; ++r)
                pw[((lane >> 4) * 4 + r) * 64 + key] = f2bf(e[nf][r]);
        }
        __syncthreads();

        // O += P·V  (B-operand = Vt rows)
#pragma unroll
        for (int ks = 0; ks < 2; ++ks) {
            bf16x8 ap = *(const bf16x8*)(pw + (lane & 15) * 64 + ks * 32 + kq);
#pragma unroll
            for (int df = 0; df < 4; ++df) {
                bf16x8 bv = *(const bf16x8*)(Vt + (df * 16 + (lane & 15)) * 64 + ks * 32 + kq);
                oacc[df] = __builtin_amdgcn_mfma_f32_16x16x32_bf16(ap, bv, oacc[df], 0, 0, 0);
            }
        }
    }

    // epilogue: normalize and store bf16
#pragma unroll
    for (int df = 0; df < 4; ++df) {
        int col = colbase + df * 16 + (lane & 15);
#pragma unroll
        for (int r = 0; r < 4; ++r) {
            int row = qt * 64 + wave * 16 + ((lane >> 4) << 2) + r;
            float v = oacc[df][r] / lrow[r];
            O[(rowbase + row) * EMBED + col] = f2bf(v);
        }
    }
}

// ---------------- launch ----------------
extern "C" void kernel_launch(void* const* d_in, const int* in_sizes, int n_in,
                              void* d_out, int out_size, void* d_ws, size_t ws_size,
                              hipStream_t stream) {
    const float* q_in = (const float*)d_in[0];
    const float* k_in = (const float*)d_in[1];
    const float* v_in = (const float*)d_in[2];
    const float* Wq = (const float*)d_in[3];
    const float* bq = (const float*)d_in[4];
    const float* Wk = (const float*)d_in[5];
    const float* bk = (const float*)d_in[6];
    const float* Wv = (const float*)d_in[7];
    const float* bv = (const float*)d_in[8];
    const float* Wo = (const float*)d_in[9];
    const float* bo = (const float*)d_in[10];
    float* out = (float*)d_out;

    const size_t XE = (size_t)ROWS * EMBED;   // 8,388,608
    const size_t WE = (size_t)EMBED * EMBED;  // 1,048,576

    unsigned short* ws = (unsigned short*)d_ws;
    unsigned short* xq = ws;
    unsigned short* xk = xq + XE;
    unsigned short* xv = xk + XE;
    unsigned short* wq = xv + XE;
    unsigned short* wk = wq + WE;
    unsigned short* wv = wk + WE;
    unsigned short* wo = wv + WE;
    unsigned short* Qp = wo + WE;
    unsigned short* Kp = Qp + XE;
    unsigned short* Vp = Kp + XE;
    unsigned short* Ap = Vp + XE;
    // total ws use: (7*XE + 4*WE)*2 bytes = ~126 MB

    // conversions
    cvt_f32_bf16<<<dim3((unsigned)(XE / 4 / 256)), 256, 0, stream>>>(q_in, xq, (int)XE);
    cvt_f32_bf16<<<dim3((unsigned)(XE / 4 / 256)), 256, 0, stream>>>(k_in, xk, (int)XE);
    cvt_f32_bf16<<<dim3((unsigned)(XE / 4 / 256)), 256, 0, stream>>>(v_in, xv, (int)XE);
    cvt_f32_bf16<<<dim3((unsigned)(WE / 4 / 256)), 256, 0, stream>>>(Wq, wq, (int)WE);
    cvt_f32_bf16<<<dim3((unsigned)(WE / 4 / 256)), 256, 0, stream>>>(Wk, wk, (int)WE);
    cvt_f32_bf16<<<dim3((unsigned)(WE / 4 / 256)), 256, 0, stream>>>(Wv, wv, (int)WE);
    cvt_f32_bf16<<<dim3((unsigned)(WE / 4 / 256)), 256, 0, stream>>>(Wo, wo, (int)WE);

    // projections: Q/K/V = x @ W^T + b  -> bf16
    dim3 gproj(EMBED / 128, ROWS / 128);  // (8, 64)
    gemm_bt<true><<<gproj, 256, 0, stream>>>(xq, wq, bq, Qp, ROWS, EMBED, EMBED);
    gemm_bt<true><<<gproj, 256, 0, stream>>>(xk, wk, bk, Kp, ROWS, EMBED, EMBED);
    gemm_bt<true><<<gproj, 256, 0, stream>>>(xv, wv, bv, Vp, ROWS, EMBED, EMBED);

    // attention
    attn<<<dim3(SEQ / 64, HEADS, BATCH), 256, 0, stream>>>(Qp, Kp, Vp, Ap);

    // output projection -> fp32
    gemm_bt<false><<<gproj, 256, 0, stream>>>(Ap, wo, bo, out, ROWS, EMBED, EMBED);
}

// Round 2
// 545.556 us; speedup vs baseline: 1.1844x; 1.1844x over previous
//
#include <hip/hip_runtime.h>
#include <stdint.h>

#define EMBED 1024
#define HEADS 16
#define HDIM 64
#define BATCH 4
#define SEQ 2048
#define ROWS (BATCH*SEQ)   // 8192
#define PADW 72            // padded LDS row width (elements); 144B = 16B-aligned, stride = 4 banks mod 32

typedef __attribute__((ext_vector_type(8))) __bf16 bf16x8;
typedef __attribute__((ext_vector_type(4))) float f32x4;

#define LDS_U32(p) ((__attribute__((address_space(3))) unsigned int*)(p))
#define GLB_U32(p) ((const __attribute__((address_space(1))) unsigned int*)(p))

__device__ inline unsigned short f2bf(float f) {
    union { float f; unsigned int u; } v; v.f = f;
    unsigned int u = v.u;
    unsigned int r = (u + 0x7FFFu + ((u >> 16) & 1u)) >> 16;
    return (unsigned short)r;
}

// ---------------- fp32 -> bf16 conversion ----------------
__global__ __launch_bounds__(256) void cvt_f32_bf16(const float* __restrict__ src,
                                                    unsigned short* __restrict__ dst,
                                                    int n) {
    int i = (blockIdx.x * 256 + threadIdx.x) * 4;
    if (i < n) {
        float4 v = *(const float4*)(src + i);
        uint2 p;
        p.x = (unsigned)f2bf(v.x) | ((unsigned)f2bf(v.y) << 16);
        p.y = (unsigned)f2bf(v.z) | ((unsigned)f2bf(v.w) << 16);
        *(uint2*)(dst + i) = p;
    }
}

// ---------------- bf16 GEMM, C = A @ B^T + bias ----------------
// A: [M][K] bf16 row-major, B: [N][K] bf16 row-major. 128x128 tile, BK=32,
// 256 threads (4 waves 2x2). Staging via global_load_lds width=16 (m97 pattern).
template <bool OUT_BF16>
__global__ __launch_bounds__(256) void gemm_bt(const unsigned short* __restrict__ A,
                                               const unsigned short* __restrict__ B,
                                               const float* __restrict__ bias,
                                               void* __restrict__ C,
                                               int M, int N, int K) {
    __shared__ unsigned short As[128 * 32];
    __shared__ unsigned short Bs[128 * 32];

    const int tid  = threadIdx.x;
    const int lane = tid & 63;
    const int wave = tid >> 6;
    const int wm   = wave & 1;
    const int wn   = wave >> 1;
    const int tileM = blockIdx.y * 128;
    const int tileN = blockIdx.x * 128;

    f32x4 acc[4][4] = {};

    for (int k0 = 0; k0 < K; k0 += 32) {
        __syncthreads();   // previous iteration's LDS reads complete
#pragma unroll
        for (int s = 0; s < 2; ++s) {
            int j = tid + s * 256;          // 16B chunk index; LDS addr = j*16B (lane-order contiguous)
            int r = j >> 2;
            int c = (j & 3) * 8;
            __builtin_amdgcn_global_load_lds(GLB_U32(A + (size_t)(tileM + r) * K + k0 + c),
                                             LDS_U32(As + j * 8), 16, 0, 0);
            __builtin_amdgcn_global_load_lds(GLB_U32(B + (size_t)(tileN + r) * K + k0 + c),
                                             LDS_U32(Bs + j * 8), 16, 0, 0);
        }
        __syncthreads();   // drains vmcnt before barrier

        bf16x8 a[4], b[4];
        const int kk = (lane >> 4) * 8;
#pragma unroll
        for (int i = 0; i < 4; ++i) {
            a[i] = *(const bf16x8*)(As + (wm * 64 + i * 16 + (lane & 15)) * 32 + kk);
            b[i] = *(const bf16x8*)(Bs + (wn * 64 + i * 16 + (lane & 15)) * 32 + kk);
        }
#pragma unroll
        for (int i = 0; i < 4; ++i)
#pragma unroll
            for (int jn = 0; jn < 4; ++jn)
                acc[i][jn] = __builtin_amdgcn_mfma_f32_16x16x32_bf16(a[i], b[jn], acc[i][jn], 0, 0, 0);
    }

    // epilogue: C/D layout col = lane&15, row = (lane>>4)*4 + r
#pragma unroll
    for (int i = 0; i < 4; ++i) {
        int row0 = tileM + wm * 64 + i * 16 + ((lane >> 4) << 2);
#pragma unroll
        for (int jn = 0; jn < 4; ++jn) {
            int col = tileN + wn * 64 + jn * 16 + (lane & 15);
            float bv = bias[col];
#pragma unroll
            for (int r = 0; r < 4; ++r) {
                float v = acc[i][jn][r] + bv;
                if (OUT_BF16)
                    ((unsigned short*)C)[(size_t)(row0 + r) * N + col] = f2bf(v);
                else
                    ((float*)C)[(size_t)(row0 + r) * N + col] = v;
            }
        }
    }
}

// ---------------- V transpose ----------------
// src: [b*SEQ+seq][EMBED] bf16 -> dst: [(b*HEADS+h)*HDIM + d][SEQ] bf16.
// Pad-65 LDS tile: both scalar phases are bank-conflict-free (65 = 1 mod 64).
__global__ __launch_bounds__(256) void transpose_v(const unsigned short* __restrict__ src,
                                                   unsigned short* __restrict__ dst) {
    __shared__ unsigned short T[64 * 65];
    const int tid = threadIdx.x;
    const int st = blockIdx.x;   // seq tile
    const int h  = blockIdx.y;
    const int b  = blockIdx.z;

#pragma unroll
    for (int s = 0; s < 2; ++s) {
        int j = tid + s * 256;
        int r = j >> 3;            // seq within tile
        int c = (j & 7) * 8;       // dim offset
        unsigned short tmp[8];
        *(uint4*)tmp = *(const uint4*)(src + ((size_t)b * SEQ + st * 64 + r) * EMBED + h * HDIM + c);
#pragma unroll
        for (int i = 0; i < 8; ++i)
            T[r * 65 + c + i] = tmp[i];
    }
    __syncthreads();
#pragma unroll
    for (int s = 0; s < 2; ++s) {
        int j = tid + s * 256;
        int d  = j >> 3;           // dim
        int c8 = (j & 7) * 8;      // seq offset
        unsigned short tmp[8];
#pragma unroll
        for (int i = 0; i < 8; ++i)
            tmp[i] = T[(c8 + i) * 65 + d];
        *(uint4*)(dst + ((size_t)(b * HEADS + h) * HDIM + d) * SEQ + st * 64 + c8) = *(uint4*)tmp;
    }
}

// ---------------- flash attention ----------------
// One block per (qt, h, b): 64 query rows, 4 waves; wave w owns rows [16w,16w+16).
// V is pre-transposed: Vt[(b*H+h)*64 + d][seq]. All LDS rows padded to 72.
__global__ __launch_bounds__(256) void attn(const unsigned short* __restrict__ Q,
                                            const unsigned short* __restrict__ Kp,
                                            const unsigned short* __restrict__ Vt,
                                            unsigned short* __restrict__ O) {
    __shared__ unsigned short Qs[64 * PADW];
    __shared__ unsigned short Ks[64 * PADW];
    __shared__ unsigned short Vs[64 * PADW];   // Vs[d][key]
    __shared__ unsigned short Ps[64 * PADW];   // P rows (waves own disjoint rows)

    const int tid  = threadIdx.x;
    const int lane = tid & 63;
    const int wave = tid >> 6;
    const int qt = blockIdx.x;
    const int h  = blockIdx.y;
    const int b  = blockIdx.z;

    const size_t rowbase = (size_t)b * SEQ;
    const int colbase = h * HDIM;
    const size_t vtbase = (size_t)(b * HEADS + h) * HDIM;

    // stage Q tile (64x64)
#pragma unroll
    for (int s = 0; s < 2; ++s) {
        int j = tid + s * 256;
        int r = j >> 3;
        int c = (j & 7) * 8;
        uint4 v = *(const uint4*)(Q + (rowbase + qt * 64 + r) * EMBED + colbase + c);
        *(uint4*)(Qs + r * PADW + c) = v;
    }

    float mrow[4], lrow[4];
#pragma unroll
    for (int r = 0; r < 4; ++r) { mrow[r] = -1e30f; lrow[r] = 0.f; }
    f32x4 oacc[4] = {};

    const float scale = 0.03125f; // 1/sqrt(1024)

    for (int t = 0; t < 32; ++t) {
        __syncthreads();
        // stage K tile and V^T tile (both coalesced, padded rows)
#pragma unroll
        for (int s = 0; s < 2; ++s) {
            int j = tid + s * 256;
            int r = j >> 3;
            int c = (j & 7) * 8;
            uint4 vk = *(const uint4*)(Kp + (rowbase + t * 64 + r) * EMBED + colbase + c);
            *(uint4*)(Ks + r * PADW + c) = vk;
            uint4 vv = *(const uint4*)(Vt + (vtbase + r) * SEQ + t * 64 + c);
            *(uint4*)(Vs + r * PADW + c) = vv;
        }
        __syncthreads();

        // S = Q·K^T for this wave's 16 rows
        f32x4 s_acc[4] = {};
        const int kq = (lane >> 4) * 8;
#pragma unroll
        for (int ks = 0; ks < 2; ++ks) {
            bf16x8 aq = *(const bf16x8*)(Qs + (wave * 16 + (lane & 15)) * PADW + ks * 32 + kq);
#pragma unroll
            for (int nf = 0; nf < 4; ++nf) {
                bf16x8 bk = *(const bf16x8*)(Ks + (nf * 16 + (lane & 15)) * PADW + ks * 32 + kq);
                s_acc[nf] = __builtin_amdgcn_mfma_f32_16x16x32_bf16(aq, bk, s_acc[nf], 0, 0, 0);
            }
        }

        // online softmax (each lane owns 4 rows)
        float e[4][4];
        float rmax[4];
#pragma unroll
        for (int r = 0; r < 4; ++r) rmax[r] = -1e30f;
#pragma unroll
        for (int nf = 0; nf < 4; ++nf)
#pragma unroll
            for (int r = 0; r < 4; ++r) {
                float x = s_acc[nf][r] * scale;
                e[nf][r] = x;
                rmax[r] = fmaxf(rmax[r], x);
            }
#pragma unroll
        for (int off = 1; off < 16; off <<= 1)
#pragma unroll
            for (int r = 0; r < 4; ++r)
                rmax[r] = fmaxf(rmax[r], __shfl_xor(rmax[r], off));
        float alpha[4];
#pragma unroll
        for (int r = 0; r < 4; ++r) {
            float mnew = fmaxf(mrow[r], rmax[r]);
            alpha[r] = __expf(mrow[r] - mnew);
            mrow[r] = mnew;
        }
        float rsum[4] = {0.f, 0.f, 0.f, 0.f};
#pragma unroll
        for (int nf = 0; nf < 4; ++nf)
#pragma unroll
            for (int r = 0; r < 4; ++r) {
                float p = __expf(e[nf][r] - mrow[r]);
                e[nf][r] = p;
                rsum[r] += p;
            }
#pragma unroll
        for (int off = 1; off < 16; off <<= 1)
#pragma unroll
            for (int r = 0; r < 4; ++r)
                rsum[r] += __shfl_xor(rsum[r], off);
#pragma unroll
        for (int r = 0; r < 4; ++r)
            lrow[r] = lrow[r] * alpha[r] + rsum[r];
#pragma unroll
        for (int df = 0; df < 4; ++df)
#pragma unroll
            for (int r = 0; r < 4; ++r)
                oacc[df][r] *= alpha[r];

        // write P (C-layout) to LDS bf16 (padded rows: 4-way max on scalar writes)
#pragma unroll
        for (int nf = 0; nf < 4; ++nf) {
            int key = nf * 16 + (lane & 15);
#pragma unroll
            for (int r = 0; r < 4; ++r)
                Ps[(wave * 16 + (lane >> 4) * 4 + r) * PADW + key] = f2bf(e[nf][r]);
        }
        __syncthreads();

        // O += P·V
#pragma unroll
        for (int ks = 0; ks < 2; ++ks) {
            bf16x8 ap = *(const bf16x8*)(Ps + (wave * 16 + (lane & 15)) * PADW + ks * 32 + kq);
#pragma unroll
            for (int df = 0; df < 4; ++df) {
                bf16x8 bv = *(const bf16x8*)(Vs + (df * 16 + (lane & 15)) * PADW + ks * 32 + kq);
                oacc[df] = __builtin_amdgcn_mfma_f32_16x16x32_bf16(ap, bv, oacc[df], 0, 0, 0);
            }
        }
    }

    // epilogue: normalize and store bf16
#pragma unroll
    for (int df = 0; df < 4; ++df) {
        int col = colbase + df * 16 + (lane & 15);
#pragma unroll
        for (int r = 0; r < 4; ++r) {
            int row = qt * 64 + wave * 16 + ((lane >> 4) << 2) + r;
            float v = oacc[df][r] / lrow[r];
            O[(rowbase + row) * EMBED + col] = f2bf(v);
        }
    }
}

// ---------------- launch ----------------
extern "C" void kernel_launch(void* const* d_in, const int* in_sizes, int n_in,
                              void* d_out, int out_size, void* d_ws, size_t ws_size,
                              hipStream_t stream) {
    const float* q_in = (const float*)d_in[0];
    const float* k_in = (const float*)d_in[1];
    const float* v_in = (const float*)d_in[2];
    const float* Wq = (const float*)d_in[3];
    const float* bq = (const float*)d_in[4];
    const float* Wk = (const float*)d_in[5];
    const float* bk = (const float*)d_in[6];
    const float* Wv = (const float*)d_in[7];
    const float* bv = (const float*)d_in[8];
    const float* Wo = (const float*)d_in[9];
    const float* bo = (const float*)d_in[10];
    float* out = (float*)d_out;

    const size_t XE = (size_t)ROWS * EMBED;   // 8,388,608
    const size_t WE = (size_t)EMBED * EMBED;  // 1,048,576

    unsigned short* ws = (unsigned short*)d_ws;
    unsigned short* xq = ws;
    unsigned short* xk = xq + XE;
    unsigned short* xv = xk + XE;       // reused as V^T after the V projection
    unsigned short* wq = xv + XE;
    unsigned short* wk = wq + WE;
    unsigned short* wv = wk + WE;
    unsigned short* wo = wv + WE;
    unsigned short* Qp = wo + WE;
    unsigned short* Kp = Qp + XE;
    unsigned short* Vp = Kp + XE;
    unsigned short* Ap = Vp + XE;
    // total ws use: (7*XE + 4*WE)*2 bytes = ~126 MB (same as R1)

    cvt_f32_bf16<<<dim3((unsigned)(XE / 4 / 256)), 256, 0, stream>>>(q_in, xq, (int)XE);
    cvt_f32_bf16<<<dim3((unsigned)(XE / 4 / 256)), 256, 0, stream>>>(k_in, xk, (int)XE);
    cvt_f32_bf16<<<dim3((unsigned)(XE / 4 / 256)), 256, 0, stream>>>(v_in, xv, (int)XE);
    cvt_f32_bf16<<<dim3((unsigned)(WE / 4 / 256)), 256, 0, stream>>>(Wq, wq, (int)WE);
    cvt_f32_bf16<<<dim3((unsigned)(WE / 4 / 256)), 256, 0, stream>>>(Wk, wk, (int)WE);
    cvt_f32_bf16<<<dim3((unsigned)(WE / 4 / 256)), 256, 0, stream>>>(Wv, wv, (int)WE);
    cvt_f32_bf16<<<dim3((unsigned)(WE / 4 / 256)), 256, 0, stream>>>(Wo, wo, (int)WE);

    dim3 gproj(EMBED / 128, ROWS / 128);  // (8, 64)
    gemm_bt<true><<<gproj, 256, 0, stream>>>(xq, wq, bq, Qp, ROWS, EMBED, EMBED);
    gemm_bt<true><<<gproj, 256, 0, stream>>>(xk, wk, bk, Kp, ROWS, EMBED, EMBED);
    gemm_bt<true><<<gproj, 256, 0, stream>>>(xv, wv, bv, Vp, ROWS, EMBED, EMBED);

    // V^T into xv (bf16 V input is dead after the V projection)
    transpose_v<<<dim3(SEQ / 64, HEADS, BATCH), 256, 0, stream>>>(Vp, xv);

    attn<<<dim3(SEQ / 64, HEADS, BATCH), 256, 0, stream>>>(Qp, Kp, xv, Ap);

    gemm_bt<false><<<gproj, 256, 0, stream>>>(Ap, wo, bo, out, ROWS, EMBED, EMBED);
}

// Round 3
// 430.605 us; speedup vs baseline: 1.5005x; 1.2670x over previous
//
#include <hip/hip_runtime.h>
#include <stdint.h>

#define EMBED 1024
#define HEADS 16
#define HDIM 64
#define BATCH 4
#define SEQ 2048
#define ROWS (BATCH*SEQ)   // 8192

typedef __attribute__((ext_vector_type(8))) __bf16 bf16x8;
typedef __attribute__((ext_vector_type(4))) float f32x4;

#define LDS_U32(p) ((__attribute__((address_space(3))) unsigned int*)(p))
#define GLB_U32(p) ((const __attribute__((address_space(1))) unsigned int*)(p))

__device__ inline unsigned short f2bf(float f) {   // RNE
    union { float f; unsigned int u; } v; v.f = f;
    unsigned int u = v.u;
    return (unsigned short)((u + 0x7FFFu + ((u >> 16) & 1u)) >> 16);
}
__device__ inline unsigned short f2bf_trunc(float f) {
    union { float f; unsigned int u; } v; v.f = f;
    return (unsigned short)(v.u >> 16);
}

// ---------------- fp32 -> bf16 conversions (merged launches) ----------------
__global__ __launch_bounds__(256) void cvt3(const float* __restrict__ s0, const float* __restrict__ s1,
                                            const float* __restrict__ s2,
                                            unsigned short* __restrict__ d0, unsigned short* __restrict__ d1,
                                            unsigned short* __restrict__ d2) {
    const float* src = (blockIdx.y == 0) ? s0 : (blockIdx.y == 1) ? s1 : s2;
    unsigned short* dst = (blockIdx.y == 0) ? d0 : (blockIdx.y == 1) ? d1 : d2;
    int i = (blockIdx.x * 256 + threadIdx.x) * 4;
    float4 v = *(const float4*)(src + i);
    uint2 p;
    p.x = (unsigned)f2bf(v.x) | ((unsigned)f2bf(v.y) << 16);
    p.y = (unsigned)f2bf(v.z) | ((unsigned)f2bf(v.w) << 16);
    *(uint2*)(dst + i) = p;
}
__global__ __launch_bounds__(256) void cvt4(const float* __restrict__ s0, const float* __restrict__ s1,
                                            const float* __restrict__ s2, const float* __restrict__ s3,
                                            unsigned short* __restrict__ dst, int stride) {
    const float* src = (blockIdx.y == 0) ? s0 : (blockIdx.y == 1) ? s1 : (blockIdx.y == 2) ? s2 : s3;
    unsigned short* d = dst + (size_t)blockIdx.y * stride;
    int i = (blockIdx.x * 256 + threadIdx.x) * 4;
    float4 v = *(const float4*)(src + i);
    uint2 p;
    p.x = (unsigned)f2bf(v.x) | ((unsigned)f2bf(v.y) << 16);
    p.y = (unsigned)f2bf(v.z) | ((unsigned)f2bf(v.w) << 16);
    *(uint2*)(d + i) = p;
}

// ---------------- bf16 GEMM, C = A @ B^T + bias (m97 pattern) ----------------
template <bool OUT_BF16>
__global__ __launch_bounds__(256) void gemm_bt(const unsigned short* __restrict__ A,
                                               const unsigned short* __restrict__ B,
                                               const float* __restrict__ bias,
                                               void* __restrict__ C,
                                               int M, int N, int K) {
    __shared__ unsigned short As[128 * 32];
    __shared__ unsigned short Bs[128 * 32];

    const int tid  = threadIdx.x;
    const int lane = tid & 63;
    const int wave = tid >> 6;
    const int wm   = wave & 1;
    const int wn   = wave >> 1;
    const int tileM = blockIdx.y * 128;
    const int tileN = blockIdx.x * 128;

    f32x4 acc[4][4] = {};

    for (int k0 = 0; k0 < K; k0 += 32) {
        __syncthreads();
#pragma unroll
        for (int s = 0; s < 2; ++s) {
            int j = tid + s * 256;
            int r = j >> 2;
            int c = (j & 3) * 8;
            __builtin_amdgcn_global_load_lds(GLB_U32(A + (size_t)(tileM + r) * K + k0 + c),
                                             LDS_U32(As + j * 8), 16, 0, 0);
            __builtin_amdgcn_global_load_lds(GLB_U32(B + (size_t)(tileN + r) * K + k0 + c),
                                             LDS_U32(Bs + j * 8), 16, 0, 0);
        }
        __syncthreads();

        bf16x8 a[4], b[4];
        const int kk = (lane >> 4) * 8;
#pragma unroll
        for (int i = 0; i < 4; ++i) {
            a[i] = *(const bf16x8*)(As + (wm * 64 + i * 16 + (lane & 15)) * 32 + kk);
            b[i] = *(const bf16x8*)(Bs + (wn * 64 + i * 16 + (lane & 15)) * 32 + kk);
        }
#pragma unroll
        for (int i = 0; i < 4; ++i)
#pragma unroll
            for (int jn = 0; jn < 4; ++jn)
                acc[i][jn] = __builtin_amdgcn_mfma_f32_16x16x32_bf16(a[i], b[jn], acc[i][jn], 0, 0, 0);
    }

#pragma unroll
    for (int i = 0; i < 4; ++i) {
        int row0 = tileM + wm * 64 + i * 16 + ((lane >> 4) << 2);
#pragma unroll
        for (int jn = 0; jn < 4; ++jn) {
            int col = tileN + wn * 64 + jn * 16 + (lane & 15);
            float bv = bias[col];
#pragma unroll
            for (int r = 0; r < 4; ++r) {
                float v = acc[i][jn][r] + bv;
                if (OUT_BF16)
                    ((unsigned short*)C)[(size_t)(row0 + r) * N + col] = f2bf(v);
                else
                    ((float*)C)[(size_t)(row0 + r) * N + col] = v;
            }
        }
    }
}

// ---------------- V transpose ----------------
// src: [b*SEQ+seq][EMBED] -> dst: [(b*HEADS+h)*HDIM + d][SEQ]
__global__ __launch_bounds__(256) void transpose_v(const unsigned short* __restrict__ src,
                                                   unsigned short* __restrict__ dst) {
    __shared__ unsigned short T[64 * 65];
    const int tid = threadIdx.x;
    const int st = blockIdx.x;
    const int h  = blockIdx.y;
    const int b  = blockIdx.z;

#pragma unroll
    for (int s = 0; s < 2; ++s) {
        int j = tid + s * 256;
        int r = j >> 3;
        int c = (j & 7) * 8;
        unsigned short tmp[8];
        *(uint4*)tmp = *(const uint4*)(src + ((size_t)b * SEQ + st * 64 + r) * EMBED + h * HDIM + c);
#pragma unroll
        for (int i = 0; i < 8; ++i)
            T[r * 65 + c + i] = tmp[i];
    }
    __syncthreads();
#pragma unroll
    for (int s = 0; s < 2; ++s) {
        int j = tid + s * 256;
        int d  = j >> 3;
        int c8 = (j & 7) * 8;
        unsigned short tmp[8];
#pragma unroll
        for (int i = 0; i < 8; ++i)
            tmp[i] = T[(c8 + i) * 65 + d];
        *(uint4*)(dst + ((size_t)(b * HEADS + h) * HDIM + d) * SEQ + st * 64 + c8) = *(uint4*)tmp;
    }
}

// ---------------- flash attention (no-max streaming softmax) ----------------
// Block = 128 q-rows x one (b,h). 4 waves; wave owns rows [32w, 32w+32).
// XOR-swizzled LDS (chunk ^= row&7): conflict-free b128 reads, no padding.
// No running max (|s*scale| <= ~1.7 by distribution), row-sum deferred to epilogue.
__global__ __launch_bounds__(256) void attn(const unsigned short* __restrict__ Q,
                                            const unsigned short* __restrict__ Kp,
                                            const unsigned short* __restrict__ Vt,
                                            unsigned short* __restrict__ O) {
    __shared__ unsigned short Qs[128 * 64];
    __shared__ unsigned short Ks[64 * 64];
    __shared__ unsigned short Vs[64 * 64];   // Vs[d][key]
    __shared__ unsigned short Ps[128 * 64];  // per-wave-disjoint rows

    const int tid  = threadIdx.x;
    const int lane = tid & 63;
    const int wave = tid >> 6;
    const int l15  = lane & 15;
    const int quad = lane >> 4;
    const int qt = blockIdx.x;
    const int h  = blockIdx.y;
    const int b  = blockIdx.z;

    const size_t rowbase = (size_t)b * SEQ;
    const int colbase = h * HDIM;
    const size_t vtbase = (size_t)(b * HEADS + h) * HDIM;

    // stage Q tile (128x64), swizzled
#pragma unroll
    for (int s = 0; s < 4; ++s) {
        int j = tid + s * 256;
        int r = j >> 3;
        int c8 = j & 7;
        uint4 v = *(const uint4*)(Q + (rowbase + qt * 128 + r) * EMBED + colbase + c8 * 8);
        *(uint4*)(Qs + r * 64 + (c8 ^ (r & 7)) * 8) = v;
    }
    __syncthreads();

    // hoist Q A-fragments (loop-invariant)
    bf16x8 aq[2][2];
#pragma unroll
    for (int mf = 0; mf < 2; ++mf)
#pragma unroll
        for (int ks = 0; ks < 2; ++ks) {
            int row = wave * 32 + mf * 16 + l15;
            int ch = (ks * 4 + quad) ^ (row & 7);
            aq[mf][ks] = *(const bf16x8*)(Qs + row * 64 + ch * 8);
        }

    f32x4 oacc[2][4] = {};
    float lsum[2][4] = {};
    const float cexp = 0.045084436f;  // (1/32) * log2(e)

    for (int t = 0; t < 32; ++t) {
        __syncthreads();
#pragma unroll
        for (int s = 0; s < 2; ++s) {
            int j = tid + s * 256;
            int r = j >> 3;
            int c8 = j & 7;
            int ch = c8 ^ (r & 7);
            uint4 vk = *(const uint4*)(Kp + (rowbase + t * 64 + r) * EMBED + colbase + c8 * 8);
            *(uint4*)(Ks + r * 64 + ch * 8) = vk;
            uint4 vv = *(const uint4*)(Vt + (vtbase + r) * SEQ + t * 64 + c8 * 8);
            *(uint4*)(Vs + r * 64 + ch * 8) = vv;
        }
        __syncthreads();

        // S = Q.K^T : per wave 32 rows x 64 keys
        f32x4 sacc[2][4] = {};
#pragma unroll
        for (int ks = 0; ks < 2; ++ks)
#pragma unroll
            for (int nf = 0; nf < 4; ++nf) {
                int krow = nf * 16 + l15;
                int ch = (ks * 4 + quad) ^ (krow & 7);
                bf16x8 bk = *(const bf16x8*)(Ks + krow * 64 + ch * 8);
#pragma unroll
                for (int mf = 0; mf < 2; ++mf)
                    sacc[mf][nf] = __builtin_amdgcn_mfma_f32_16x16x32_bf16(aq[mf][ks], bk, sacc[mf][nf], 0, 0, 0);
            }

        // p = exp(s*scale); accumulate partial row sums; write P (truncated bf16)
#pragma unroll
        for (int mf = 0; mf < 2; ++mf)
#pragma unroll
            for (int nf = 0; nf < 4; ++nf) {
                int pcol = nf * 16 + l15;
#pragma unroll
                for (int r = 0; r < 4; ++r) {
                    float p = __builtin_amdgcn_exp2f(sacc[mf][nf][r] * cexp);
                    lsum[mf][r] += p;
                    int prow = wave * 32 + mf * 16 + quad * 4 + r;
                    Ps[prow * 64 + ((pcol >> 3) ^ (prow & 7)) * 8 + (pcol & 7)] = f2bf_trunc(p);
                }
            }
        // no barrier: each wave reads only its own P rows (within-wave lgkmcnt ordering)

        // O += P.V
#pragma unroll
        for (int ks = 0; ks < 2; ++ks) {
            bf16x8 ap[2];
#pragma unroll
            for (int mf = 0; mf < 2; ++mf) {
                int prow = wave * 32 + mf * 16 + l15;
                int ch = (ks * 4 + quad) ^ (prow & 7);
                ap[mf] = *(const bf16x8*)(Ps + prow * 64 + ch * 8);
            }
#pragma unroll
            for (int df = 0; df < 4; ++df) {
                int vrow = df * 16 + l15;
                int ch = (ks * 4 + quad) ^ (vrow & 7);
                bf16x8 bv = *(const bf16x8*)(Vs + vrow * 64 + ch * 8);
#pragma unroll
                for (int mf = 0; mf < 2; ++mf)
                    oacc[mf][df] = __builtin_amdgcn_mfma_f32_16x16x32_bf16(ap[mf], bv, oacc[mf][df], 0, 0, 0);
            }
        }
    }

    // epilogue: reduce row sums across the 16 lanes sharing each row, divide, store
    float rinv[2][4];
#pragma unroll
    for (int mf = 0; mf < 2; ++mf)
#pragma unroll
        for (int r = 0; r < 4; ++r) {
            float s = lsum[mf][r];
#pragma unroll
            for (int off = 1; off < 16; off <<= 1)
                s += __shfl_xor(s, off);
            rinv[mf][r] = 1.0f / s;
        }

#pragma unroll
    for (int mf = 0; mf < 2; ++mf)
#pragma unroll
        for (int df = 0; df < 4; ++df) {
            int col = colbase + df * 16 + l15;
#pragma unroll
            for (int r = 0; r < 4; ++r) {
                int row = qt * 128 + wave * 32 + mf * 16 + quad * 4 + r;
                O[(rowbase + row) * EMBED + col] = f2bf(oacc[mf][df][r] * rinv[mf][r]);
            }
        }
}

// ---------------- launch ----------------
extern "C" void kernel_launch(void* const* d_in, const int* in_sizes, int n_in,
                              void* d_out, int out_size, void* d_ws, size_t ws_size,
                              hipStream_t stream) {
    const float* q_in = (const float*)d_in[0];
    const float* k_in = (const float*)d_in[1];
    const float* v_in = (const float*)d_in[2];
    const float* Wq = (const float*)d_in[3];
    const float* bq = (const float*)d_in[4];
    const float* Wk = (const float*)d_in[5];
    const float* bk = (const float*)d_in[6];
    const float* Wv = (const float*)d_in[7];
    const float* bv = (const float*)d_in[8];
    const float* Wo = (const float*)d_in[9];
    const float* bo = (const float*)d_in[10];
    float* out = (float*)d_out;

    const size_t XE = (size_t)ROWS * EMBED;
    const size_t WE = (size_t)EMBED * EMBED;

    unsigned short* ws = (unsigned short*)d_ws;
    unsigned short* xq = ws;
    unsigned short* xk = xq + XE;
    unsigned short* xv = xk + XE;       // reused as V^T after the V projection
    unsigned short* wqkvo = xv + XE;    // 4 weight matrices contiguous
    unsigned short* wq = wqkvo;
    unsigned short* wk = wq + WE;
    unsigned short* wv = wk + WE;
    unsigned short* wo = wv + WE;
    unsigned short* Qp = wo + WE;
    unsigned short* Kp = Qp + XE;
    unsigned short* Vp = Kp + XE;
    unsigned short* Ap = Vp + XE;

    cvt3<<<dim3((unsigned)(XE / 1024), 3), 256, 0, stream>>>(q_in, k_in, v_in, xq, xk, xv);
    cvt4<<<dim3((unsigned)(WE / 1024), 4), 256, 0, stream>>>(Wq, Wk, Wv, Wo, wqkvo, (int)WE);

    dim3 gproj(EMBED / 128, ROWS / 128);
    gemm_bt<true><<<gproj, 256, 0, stream>>>(xq, wq, bq, Qp, ROWS, EMBED, EMBED);
    gemm_bt<true><<<gproj, 256, 0, stream>>>(xk, wk, bk, Kp, ROWS, EMBED, EMBED);
    gemm_bt<true><<<gproj, 256, 0, stream>>>(xv, wv, bv, Vp, ROWS, EMBED, EMBED);

    transpose_v<<<dim3(SEQ / 64, HEADS, BATCH), 256, 0, stream>>>(Vp, xv);

    attn<<<dim3(SEQ / 128, HEADS, BATCH), 256, 0, stream>>>(Qp, Kp, xv, Ap);

    gemm_bt<false><<<gproj, 256, 0, stream>>>(Ap, wo, bo, out, ROWS, EMBED, EMBED);
}

// Round 4
// 394.636 us; speedup vs baseline: 1.6373x; 1.0911x over previous
//
#include <hip/hip_runtime.h>
#include <stdint.h>

#define EMBED 1024
#define HEADS 16
#define HDIM 64
#define BATCH 4
#define SEQ 2048
#define ROWS (BATCH*SEQ)   // 8192

typedef __attribute__((ext_vector_type(8))) __bf16 bf16x8;
typedef __attribute__((ext_vector_type(4))) float f32x4;

#define LDS_U32(p) ((__attribute__((address_space(3))) unsigned int*)(p))
#define GLB_U32(p) ((const __attribute__((address_space(1))) unsigned int*)(p))

__device__ inline unsigned short f2bf(float f) {   // RNE
    union { float f; unsigned int u; } v; v.f = f;
    unsigned int u = v.u;
    return (unsigned short)((u + 0x7FFFu + ((u >> 16) & 1u)) >> 16);
}
__device__ inline unsigned short f2bf_trunc(float f) {
    union { float f; unsigned int u; } v; v.f = f;
    return (unsigned short)(v.u >> 16);
}

// ---------------- fp32 -> bf16 conversions (merged launches) ----------------
__global__ __launch_bounds__(256) void cvt3(const float* __restrict__ s0, const float* __restrict__ s1,
                                            const float* __restrict__ s2,
                                            unsigned short* __restrict__ d0, unsigned short* __restrict__ d1,
                                            unsigned short* __restrict__ d2) {
    const float* src = (blockIdx.y == 0) ? s0 : (blockIdx.y == 1) ? s1 : s2;
    unsigned short* dst = (blockIdx.y == 0) ? d0 : (blockIdx.y == 1) ? d1 : d2;
    int i = (blockIdx.x * 256 + threadIdx.x) * 4;
    float4 v = *(const float4*)(src + i);
    uint2 p;
    p.x = (unsigned)f2bf(v.x) | ((unsigned)f2bf(v.y) << 16);
    p.y = (unsigned)f2bf(v.z) | ((unsigned)f2bf(v.w) << 16);
    *(uint2*)(dst + i) = p;
}
__global__ __launch_bounds__(256) void cvt4(const float* __restrict__ s0, const float* __restrict__ s1,
                                            const float* __restrict__ s2, const float* __restrict__ s3,
                                            unsigned short* __restrict__ dst, int stride) {
    const float* src = (blockIdx.y == 0) ? s0 : (blockIdx.y == 1) ? s1 : (blockIdx.y == 2) ? s2 : s3;
    unsigned short* d = dst + (size_t)blockIdx.y * stride;
    int i = (blockIdx.x * 256 + threadIdx.x) * 4;
    float4 v = *(const float4*)(src + i);
    uint2 p;
    p.x = (unsigned)f2bf(v.x) | ((unsigned)f2bf(v.y) << 16);
    p.y = (unsigned)f2bf(v.z) | ((unsigned)f2bf(v.w) << 16);
    *(uint2*)(d + i) = p;
}

// ---------------- bf16 GEMM, C = A @ B^T + bias ----------------
// BK=64, XOR-swizzled LDS staged via global_load_lds (source-side permute keeps
// coalescing; LDS side stays linear). 16 barrier-pairs for K=1024 (was 32).
// QKV==true: blockIdx.z selects one of 3 contiguous problems (A,B,C strided).
template <bool OUT_BF16, bool QKV>
__global__ __launch_bounds__(256) void gemm_bt(const unsigned short* __restrict__ A0,
                                               const unsigned short* __restrict__ B0,
                                               const float* __restrict__ bias0,
                                               const float* __restrict__ bias1,
                                               const float* __restrict__ bias2,
                                               void* __restrict__ C0,
                                               int M, int N, int K) {
    __shared__ unsigned short As[128 * 64];
    __shared__ unsigned short Bs[128 * 64];

    const int tid  = threadIdx.x;
    const int lane = tid & 63;
    const int wave = tid >> 6;
    const int l15  = lane & 15;
    const int quad = lane >> 4;
    const int wm   = wave & 1;
    const int wn   = wave >> 1;
    const int tileM = blockIdx.y * 128;
    const int tileN = blockIdx.x * 128;

    const unsigned short* A = A0;
    const unsigned short* B = B0;
    const float* bias = bias0;
    void* C = C0;
    if (QKV) {
        int z = blockIdx.z;
        A = A0 + (size_t)z * M * K;
        B = B0 + (size_t)z * N * K;
        bias = (z == 0) ? bias0 : (z == 1) ? bias1 : bias2;
        C = (void*)((unsigned short*)C0 + (size_t)z * M * N);
    }

    f32x4 acc[4][4] = {};

    for (int k0 = 0; k0 < K; k0 += 64) {
        __syncthreads();
#pragma unroll
        for (int s = 0; s < 4; ++s) {
            int j = tid + s * 256;              // 1024 chunks of 16B per matrix
            int r = j >> 3;
            int c8 = (j & 7) ^ (r & 7);         // source-side swizzle
            __builtin_amdgcn_global_load_lds(GLB_U32(A + (size_t)(tileM + r) * K + k0 + c8 * 8),
                                             LDS_U32(As + j * 8), 16, 0, 0);
            __builtin_amdgcn_global_load_lds(GLB_U32(B + (size_t)(tileN + r) * K + k0 + c8 * 8),
                                             LDS_U32(Bs + j * 8), 16, 0, 0);
        }
        __syncthreads();

#pragma unroll
        for (int kc = 0; kc < 2; ++kc) {
            bf16x8 a[4], b[4];
#pragma unroll
            for (int i = 0; i < 4; ++i) {
                int ra = wm * 64 + i * 16 + l15;
                a[i] = *(const bf16x8*)(As + ra * 64 + (((kc * 4 + quad) ^ (ra & 7)) * 8));
                int rb = wn * 64 + i * 16 + l15;
                b[i] = *(const bf16x8*)(Bs + rb * 64 + (((kc * 4 + quad) ^ (rb & 7)) * 8));
            }
#pragma unroll
            for (int i = 0; i < 4; ++i)
#pragma unroll
                for (int jn = 0; jn < 4; ++jn)
                    acc[i][jn] = __builtin_amdgcn_mfma_f32_16x16x32_bf16(a[i], b[jn], acc[i][jn], 0, 0, 0);
        }
    }

#pragma unroll
    for (int i = 0; i < 4; ++i) {
        int row0 = tileM + wm * 64 + i * 16 + (quad << 2);
#pragma unroll
        for (int jn = 0; jn < 4; ++jn) {
            int col = tileN + wn * 64 + jn * 16 + l15;
            float bv = bias[col];
#pragma unroll
            for (int r = 0; r < 4; ++r) {
                float v = acc[i][jn][r] + bv;
                if (OUT_BF16)
                    ((unsigned short*)C)[(size_t)(row0 + r) * N + col] = f2bf(v);
                else
                    ((float*)C)[(size_t)(row0 + r) * N + col] = v;
            }
        }
    }
}

// ---------------- V transpose ----------------
// src: [b*SEQ+seq][EMBED] -> dst: [(b*HEADS+h)*HDIM + d][SEQ]
__global__ __launch_bounds__(256) void transpose_v(const unsigned short* __restrict__ src,
                                                   unsigned short* __restrict__ dst) {
    __shared__ unsigned short T[64 * 65];
    const int tid = threadIdx.x;
    const int st = blockIdx.x;
    const int h  = blockIdx.y;
    const int b  = blockIdx.z;

#pragma unroll
    for (int s = 0; s < 2; ++s) {
        int j = tid + s * 256;
        int r = j >> 3;
        int c = (j & 7) * 8;
        unsigned short tmp[8];
        *(uint4*)tmp = *(const uint4*)(src + ((size_t)b * SEQ + st * 64 + r) * EMBED + h * HDIM + c);
#pragma unroll
        for (int i = 0; i < 8; ++i)
            T[r * 65 + c + i] = tmp[i];
    }
    __syncthreads();
#pragma unroll
    for (int s = 0; s < 2; ++s) {
        int j = tid + s * 256;
        int d  = j >> 3;
        int c8 = (j & 7) * 8;
        unsigned short tmp[8];
#pragma unroll
        for (int i = 0; i < 8; ++i)
            tmp[i] = T[(c8 + i) * 65 + d];
        *(uint4*)(dst + ((size_t)(b * HEADS + h) * HDIM + d) * SEQ + st * 64 + c8) = *(uint4*)tmp;
    }
}

// ---------------- flash attention (no-max streaming softmax) ----------------
// Block = 128 q-rows x one (b,h); 4 waves; wave owns rows [32w, 32w+32).
// LDS 32KB (Ps aliases Qs after Q-frag hoist) -> 4 blocks/CU, grid 1024 fully
// resident in one pass. All staging via global_load_lds with source-side swizzle.
__global__ __launch_bounds__(256) void attn(const unsigned short* __restrict__ Q,
                                            const unsigned short* __restrict__ Kp,
                                            const unsigned short* __restrict__ Vt,
                                            unsigned short* __restrict__ O) {
    __shared__ unsigned short QPs[128 * 64];   // Q tile, then reused as P
    __shared__ unsigned short Ks[64 * 64];
    __shared__ unsigned short Vs[64 * 64];     // Vs[d][key]

    const int tid  = threadIdx.x;
    const int lane = tid & 63;
    const int wave = tid >> 6;
    const int l15  = lane & 15;
    const int quad = lane >> 4;
    const int qt = blockIdx.x;
    const int h  = blockIdx.y;
    const int b  = blockIdx.z;

    const size_t rowbase = (size_t)b * SEQ;
    const int colbase = h * HDIM;
    const size_t vtbase = (size_t)(b * HEADS + h) * HDIM;

    // stage Q tile (128x64) via global_load_lds, source-side swizzle
#pragma unroll
    for (int s = 0; s < 4; ++s) {
        int j = tid + s * 256;
        int r = j >> 3;
        int c8 = (j & 7) ^ (r & 7);
        __builtin_amdgcn_global_load_lds(GLB_U32(Q + (rowbase + qt * 128 + r) * EMBED + colbase + c8 * 8),
                                         LDS_U32(QPs + j * 8), 16, 0, 0);
    }
    __syncthreads();

    // hoist Q A-fragments (loop-invariant); afterwards QPs is free for P
    bf16x8 aq[2][2];
#pragma unroll
    for (int mf = 0; mf < 2; ++mf)
#pragma unroll
        for (int ks = 0; ks < 2; ++ks) {
            int row = wave * 32 + mf * 16 + l15;
            int ch = (ks * 4 + quad) ^ (row & 7);
            aq[mf][ks] = *(const bf16x8*)(QPs + row * 64 + ch * 8);
        }

    f32x4 oacc[2][4] = {};
    float lsum[2][4] = {};
    const float cexp = 0.045084436f;  // (1/32) * log2(e)

    for (int t = 0; t < 32; ++t) {
        __syncthreads();
#pragma unroll
        for (int s = 0; s < 2; ++s) {
            int j = tid + s * 256;
            int r = j >> 3;
            int c8 = (j & 7) ^ (r & 7);
            __builtin_amdgcn_global_load_lds(GLB_U32(Kp + (rowbase + t * 64 + r) * EMBED + colbase + c8 * 8),
                                             LDS_U32(Ks + j * 8), 16, 0, 0);
            __builtin_amdgcn_global_load_lds(GLB_U32(Vt + (vtbase + r) * SEQ + t * 64 + c8 * 8),
                                             LDS_U32(Vs + j * 8), 16, 0, 0);
        }
        __syncthreads();

        // S = Q.K^T : per wave 32 rows x 64 keys
        f32x4 sacc[2][4] = {};
#pragma unroll
        for (int ks = 0; ks < 2; ++ks)
#pragma unroll
            for (int nf = 0; nf < 4; ++nf) {
                int krow = nf * 16 + l15;
                int ch = (ks * 4 + quad) ^ (krow & 7);
                bf16x8 bk = *(const bf16x8*)(Ks + krow * 64 + ch * 8);
#pragma unroll
                for (int mf = 0; mf < 2; ++mf)
                    sacc[mf][nf] = __builtin_amdgcn_mfma_f32_16x16x32_bf16(aq[mf][ks], bk, sacc[mf][nf], 0, 0, 0);
            }

        // p = exp2(s*c); partial row sums; write P (truncated bf16, swizzled)
#pragma unroll
        for (int mf = 0; mf < 2; ++mf)
#pragma unroll
            for (int nf = 0; nf < 4; ++nf) {
                int pcol = nf * 16 + l15;
#pragma unroll
                for (int r = 0; r < 4; ++r) {
                    float p = __builtin_amdgcn_exp2f(sacc[mf][nf][r] * cexp);
                    lsum[mf][r] += p;
                    int prow = wave * 32 + mf * 16 + quad * 4 + r;
                    QPs[prow * 64 + ((pcol >> 3) ^ (prow & 7)) * 8 + (pcol & 7)] = f2bf_trunc(p);
                }
            }
        // no barrier: each wave reads only its own P rows

        // O += P.V
#pragma unroll
        for (int ks = 0; ks < 2; ++ks) {
            bf16x8 ap[2];
#pragma unroll
            for (int mf = 0; mf < 2; ++mf) {
                int prow = wave * 32 + mf * 16 + l15;
                int ch = (ks * 4 + quad) ^ (prow & 7);
                ap[mf] = *(const bf16x8*)(QPs + prow * 64 + ch * 8);
            }
#pragma unroll
            for (int df = 0; df < 4; ++df) {
                int vrow = df * 16 + l15;
                int ch = (ks * 4 + quad) ^ (vrow & 7);
                bf16x8 bv = *(const bf16x8*)(Vs + vrow * 64 + ch * 8);
#pragma unroll
                for (int mf = 0; mf < 2; ++mf)
                    oacc[mf][df] = __builtin_amdgcn_mfma_f32_16x16x32_bf16(ap[mf], bv, oacc[mf][df], 0, 0, 0);
            }
        }
    }

    // epilogue: reduce row sums across the 16 lanes sharing each row, divide, store
    float rinv[2][4];
#pragma unroll
    for (int mf = 0; mf < 2; ++mf)
#pragma unroll
        for (int r = 0; r < 4; ++r) {
            float s = lsum[mf][r];
#pragma unroll
            for (int off = 1; off < 16; off <<= 1)
                s += __shfl_xor(s, off);
            rinv[mf][r] = 1.0f / s;
        }

#pragma unroll
    for (int mf = 0; mf < 2; ++mf)
#pragma unroll
        for (int df = 0; df < 4; ++df) {
            int col = colbase + df * 16 + l15;
#pragma unroll
            for (int r = 0; r < 4; ++r) {
                int row = qt * 128 + wave * 32 + mf * 16 + quad * 4 + r;
                O[(rowbase + row) * EMBED + col] = f2bf(oacc[mf][df][r] * rinv[mf][r]);
            }
        }
}

// ---------------- launch ----------------
extern "C" void kernel_launch(void* const* d_in, const int* in_sizes, int n_in,
                              void* d_out, int out_size, void* d_ws, size_t ws_size,
                              hipStream_t stream) {
    const float* q_in = (const float*)d_in[0];
    const float* k_in = (const float*)d_in[1];
    const float* v_in = (const float*)d_in[2];
    const float* Wq = (const float*)d_in[3];
    const float* bq = (const float*)d_in[4];
    const float* Wk = (const float*)d_in[5];
    const float* bk = (const float*)d_in[6];
    const float* Wv = (const float*)d_in[7];
    const float* bv = (const float*)d_in[8];
    const float* Wo = (const float*)d_in[9];
    const float* bo = (const float*)d_in[10];
    float* out = (float*)d_out;

    const size_t XE = (size_t)ROWS * EMBED;
    const size_t WE = (size_t)EMBED * EMBED;

    unsigned short* ws = (unsigned short*)d_ws;
    unsigned short* xq = ws;            // xq,xk,xv contiguous (fused QKV A-operand)
    unsigned short* xk = xq + XE;
    unsigned short* xv = xk + XE;       // reused as V^T after the V projection
    unsigned short* wqkvo = xv + XE;    // 4 weight matrices contiguous
    unsigned short* wo = wqkvo + 3 * WE;
    unsigned short* Qp = wo + WE;       // Qp,Kp,Vp contiguous (fused QKV C)
    unsigned short* Kp = Qp + XE;
    unsigned short* Vp = Kp + XE;
    unsigned short* Ap = Vp + XE;

    cvt3<<<dim3((unsigned)(XE / 1024), 3), 256, 0, stream>>>(q_in, k_in, v_in, xq, xk, xv);
    cvt4<<<dim3((unsigned)(WE / 1024), 4), 256, 0, stream>>>(Wq, Wk, Wv, Wo, wqkvo, (int)WE);

    // fused Q/K/V projections
    gemm_bt<true, true><<<dim3(EMBED / 128, ROWS / 128, 3), 256, 0, stream>>>(
        xq, wqkvo, bq, bk, bv, Qp, ROWS, EMBED, EMBED);

    transpose_v<<<dim3(SEQ / 64, HEADS, BATCH), 256, 0, stream>>>(Vp, xv);

    attn<<<dim3(SEQ / 128, HEADS, BATCH), 256, 0, stream>>>(Qp, Kp, xv, Ap);

    gemm_bt<false, false><<<dim3(EMBED / 128, ROWS / 128), 256, 0, stream>>>(
        Ap, wo, bo, nullptr, nullptr, out, ROWS, EMBED, EMBED);
}